// Round 13
// baseline (11009.409 us; speedup 1.0000x reference)
//
#include <hip/hip_runtime.h>
#include <hip/hip_bf16.h>

#define SEQ 512
#define HD 1024
#define NWG 256
#define TPB 256
#define RED_OFF 131072
#define LDS_BYTES (131072 + 32768)
#define OUT_H 33554432ull
#define OUT_C 33619968ull
#define RMASK 31   // 32-slot h ring; inv cadence 16 covers slot reuse

typedef __bf16 bf16x8 __attribute__((ext_vector_type(8)));
typedef float f32x4 __attribute__((ext_vector_type(4)));

__device__ __forceinline__ unsigned short f2bf(float f) {
  __hip_bfloat16 b = __float2bfloat16(f);  // RNE
  return __builtin_bit_cast(unsigned short, b);
}
__device__ __forceinline__ float bf2f(unsigned short s) {
  return __builtin_bit_cast(float, (unsigned)s << 16);  // exact widen
}

__device__ __forceinline__ float sigm(float v) { return 1.f / (1.f + __expf(-v)); }
__device__ __forceinline__ float tanh_(float v) {
  float av = fabsf(v);
  float e = __expf(-2.f * av);
  float t = (1.f - e) / (1.f + e);
  return copysignf(t, v);
}

// async global->LDS, 16B/lane (x path only)
__device__ __forceinline__ void gl2lds(const void* g, void* l) {
  __builtin_amdgcn_global_load_lds(
      (const __attribute__((address_space(1))) void*)g,
      (__attribute__((address_space(3))) void*)l, 16, 0, 0);
}

// per-WAVE epoch wait (relaxed agent poll; no cache maintenance)
__device__ __forceinline__ void wave_wait_ge(const unsigned* a, unsigned v) {
  while (__hip_atomic_load(a, __ATOMIC_RELAXED, __HIP_MEMORY_SCOPE_AGENT) < v)
    __builtin_amdgcn_s_sleep(1);
  __builtin_amdgcn_wave_barrier();
  asm volatile("" ::: "memory");
}

// Persistent LSTM, round-13: round-12 core (4 waves, K-split 4, decoupled
// per-layer barriers, h-ring relaxed publish, symmetric epilogue) with:
//  1) h path = direct-to-REGISTER loads, 4-deep prefetch ring (no LDS stage)
//  2) early flag: h-publish drained + flag posted BEFORE out[] stores
// Math and operand order bit-identical to round 12.
__global__ __launch_bounds__(TPB, 1) void lstm_main(
    const float* __restrict__ x,
    const float* __restrict__ Wih_f,
    const float* __restrict__ Whh_f,
    const float* __restrict__ bias,
    unsigned short* h0hi, unsigned short* h0lo,
    unsigned short* h1hi, unsigned short* h1lo,
    float* __restrict__ out,
    unsigned* bar) {
  __shared__ char smem[LDS_BYTES];
  float* red = (float*)(smem + RED_OFF);

  unsigned* go0 = bar + 8192;
  unsigned* go1 = bar + 8192 + 32;

  const int w = blockIdx.x;
  const int tid = threadIdx.x;
  const int layer = w >> 7;
  const int tl = w & 127;             // index within layer; tl==0 is leader
  const int j0 = tl << 3;
  const int lane = tid & 63;
  const int kw = tid >> 6;
  const int cl = lane & 15;
  const int rg = lane >> 4;
  const int kbase = kw << 9;
  const int krel = (kw & 1) << 9;
  const bool isx = (layer == 0) && (kw < 2);

  // ---- W prologue: build hi+lo B-fragments in registers from fp32 W (RNE)
  uint4 whi[32], wlo[32];
#pragma unroll
  for (int i = 0; i < 32; ++i) {
    const int nt = i & 1, ks = i >> 1;
    const int c = nt * 16 + cl;
    const int grow = ((c >> 3) << 10) + j0 + (c & 7);
    const int kglob = kbase + (ks << 5) + (rg << 3);
    const float* src = (kglob < HD)
        ? (Wih_f + (((size_t)layer << 22) + ((size_t)grow << 10) + kglob))
        : (Whh_f + (((size_t)layer << 22) + ((size_t)grow << 10) + (kglob - HD)));
    union { unsigned short s2[8]; uint4 v; } uh, ul;
#pragma unroll
    for (int e = 0; e < 8; ++e) {
      const float vv = src[e];
      const unsigned short hb = f2bf(vv);
      uh.s2[e] = hb;
      ul.s2[e] = f2bf(vv - bf2f(hb));
    }
    whi[i] = uh.v;
    wlo[i] = ul.v;
  }

  const int u_ = cl & 7;
  const float bi  = bias[(layer << 12) + j0 + u_];
  const float bf_ = bias[(layer << 12) + 1024 + j0 + u_];
  const float bg  = bias[(layer << 12) + 2048 + j0 + u_];
  const float bo  = bias[(layer << 12) + 3072 + j0 + u_];

  float creg[4];
#pragma unroll
  for (int i = 0; i < 4; ++i) creg[i] = 0.f;

  // x staging lane constants (round-9/12 proven)
  char* stripe = smem + (kw << 14);   // buf0 stripe; buf1 = +65536
  const int xrr = lane >> 4;
  const int xjj = lane & 15;
  const int xslotE = xjj ^ xrr;       // even issues
  const int xslotO = xjj ^ (4 + xrr); // odd issues

  __syncthreads();

  for (int t = 0; t < SEQ; ++t) {
    const unsigned e = (unsigned)(t + 1);

    // ---- per-wave epoch gating (L0 x-waves: none)
    if (layer == 0) {
      if (kw >= 2) wave_wait_ge(go0, (unsigned)t);          // h0[t-1]
    } else {
      if (kw < 2) wave_wait_ge(go0, e);                     // h0[t]
      else        wave_wait_ge(go1, (unsigned)t);           // h1[t-1]
    }

    f32x4 acc[4][2];
#pragma unroll
    for (int mt = 0; mt < 4; ++mt) {
      acc[mt][0] = (f32x4){0.f, 0.f, 0.f, 0.f};
      acc[mt][1] = (f32x4){0.f, 0.f, 0.f, 0.f};
    }

    if (isx) {
      // ---- x path (unchanged round-12): LDS-staged fp32, trunc-split
      const float* pxE = x + ((size_t)(xrr * SEQ + t) << 10) + kbase + (xslotE << 2);
      const float* pxO = x + ((size_t)(xrr * SEQ + t) << 10) + kbase + (xslotO << 2);
#pragma unroll
      for (int i = 0; i < 16; ++i)
        gl2lds(((i & 1) ? pxO : pxE) + (size_t)i * 2097152, stripe + i * 1024);
#pragma unroll
      for (int s = 0; s < 8; ++s) {
        char* cb = stripe + ((s & 1) << 16);
        if (s < 7) {
          char* nb = stripe + (((s + 1) & 1) << 16);
          const int so = (s + 1) << 6;
#pragma unroll
          for (int i = 0; i < 16; ++i)
            gl2lds(((i & 1) ? pxO : pxE) + (size_t)i * 2097152 + so, nb + i * 1024);
          asm volatile("s_waitcnt vmcnt(16)" ::: "memory");
        } else {
          asm volatile("s_waitcnt vmcnt(0)" ::: "memory");
        }
#pragma unroll
        for (int ksl = 0; ksl < 2; ++ksl) {
          const int ig = (((s << 1) + ksl) << 1);
          const bf16x8 bh0 = __builtin_bit_cast(bf16x8, whi[ig]);
          const bf16x8 bh1 = __builtin_bit_cast(bf16x8, whi[ig + 1]);
          const bf16x8 bl0 = __builtin_bit_cast(bf16x8, wlo[ig]);
          const bf16x8 bl1 = __builtin_bit_cast(bf16x8, wlo[ig + 1]);
#pragma unroll
          for (int mt = 0; mt < 4; ++mt) {
            const int r = (mt << 4) + cl;
            const int a0 = (ksl << 3) + (rg << 1);
            const float4 f0 = *(const float4*)(cb + r * 256 + ((a0 ^ (cl & 7)) << 4));
            const float4 f1 = *(const float4*)(cb + r * 256 + (((a0 + 1) ^ (cl & 7)) << 4));
            union { unsigned short s2[8]; uint4 v; } uh, ul;
            const float ee[8] = {f0.x, f0.y, f0.z, f0.w, f1.x, f1.y, f1.z, f1.w};
#pragma unroll
            for (int e2 = 0; e2 < 8; ++e2) {
              const unsigned uu = __builtin_bit_cast(unsigned, ee[e2]);
              uh.s2[e2] = (unsigned short)(uu >> 16);  // trunc16 = exact bf16 hi
              ul.s2[e2] = f2bf(ee[e2] - __builtin_bit_cast(float, uu & 0xffff0000u));
            }
            const bf16x8 ah = __builtin_bit_cast(bf16x8, uh.v);
            const bf16x8 al = __builtin_bit_cast(bf16x8, ul.v);
            acc[mt][0] = __builtin_amdgcn_mfma_f32_16x16x32_bf16(ah, bh0, acc[mt][0], 0, 0, 0);
            acc[mt][1] = __builtin_amdgcn_mfma_f32_16x16x32_bf16(ah, bh1, acc[mt][1], 0, 0, 0);
            acc[mt][0] = __builtin_amdgcn_mfma_f32_16x16x32_bf16(al, bh0, acc[mt][0], 0, 0, 0);
            acc[mt][1] = __builtin_amdgcn_mfma_f32_16x16x32_bf16(al, bh1, acc[mt][1], 0, 0, 0);
            acc[mt][0] = __builtin_amdgcn_mfma_f32_16x16x32_bf16(ah, bl0, acc[mt][0], 0, 0, 0);
            acc[mt][1] = __builtin_amdgcn_mfma_f32_16x16x32_bf16(ah, bl1, acc[mt][1], 0, 0, 0);
          }
        }
      }
    } else {
      // ---- h path (round-13): direct-to-register, 4-deep prefetch ring,
      // 16 fully-unrolled K-32 steps; no LDS, no vmcnt chokepoints.
      const unsigned short *shi_, *slo_;
      if (layer == 0) {
        const int sl = (t - 1) & RMASK;
        shi_ = h0hi + (sl << 16); slo_ = h0lo + (sl << 16);
      } else if (kw < 2) {
        const int sl = t & RMASK;
        shi_ = h0hi + (sl << 16); slo_ = h0lo + (sl << 16);
      } else {
        const int sl = (t - 1) & RMASK;
        shi_ = h1hi + (sl << 16); slo_ = h1lo + (sl << 16);
      }
      const unsigned short* bh_[4];
      const unsigned short* bl_[4];
#pragma unroll
      for (int mt = 0; mt < 4; ++mt) {
        const int row = (mt << 4) + cl;
        bh_[mt] = shi_ + (row << 10) + krel + (rg << 3);
        bl_[mt] = slo_ + (row << 10) + krel + (rg << 3);
      }
      uint4 fh[4][4], fl[4][4];   // [step&3][mt] -- all indices static post-unroll
#pragma unroll
      for (int p = 0; p < 4; ++p)
#pragma unroll
        for (int mt = 0; mt < 4; ++mt) {
          fh[p][mt] = *(const uint4*)(bh_[mt] + (p << 5));
          fl[p][mt] = *(const uint4*)(bl_[mt] + (p << 5));
        }
#pragma unroll
      for (int s = 0; s < 16; ++s) {
        const bf16x8 bh0 = __builtin_bit_cast(bf16x8, whi[(s << 1)]);
        const bf16x8 bh1 = __builtin_bit_cast(bf16x8, whi[(s << 1) + 1]);
        const bf16x8 bl0 = __builtin_bit_cast(bf16x8, wlo[(s << 1)]);
        const bf16x8 bl1 = __builtin_bit_cast(bf16x8, wlo[(s << 1) + 1]);
#pragma unroll
        for (int mt = 0; mt < 4; ++mt) {
          const bf16x8 ah = __builtin_bit_cast(bf16x8, fh[s & 3][mt]);
          const bf16x8 al = __builtin_bit_cast(bf16x8, fl[s & 3][mt]);
          acc[mt][0] = __builtin_amdgcn_mfma_f32_16x16x32_bf16(ah, bh0, acc[mt][0], 0, 0, 0);
          acc[mt][1] = __builtin_amdgcn_mfma_f32_16x16x32_bf16(ah, bh1, acc[mt][1], 0, 0, 0);
          acc[mt][0] = __builtin_amdgcn_mfma_f32_16x16x32_bf16(al, bh0, acc[mt][0], 0, 0, 0);
          acc[mt][1] = __builtin_amdgcn_mfma_f32_16x16x32_bf16(al, bh1, acc[mt][1], 0, 0, 0);
          acc[mt][0] = __builtin_amdgcn_mfma_f32_16x16x32_bf16(ah, bl0, acc[mt][0], 0, 0, 0);
          acc[mt][1] = __builtin_amdgcn_mfma_f32_16x16x32_bf16(ah, bl1, acc[mt][1], 0, 0, 0);
        }
        if (s < 12) {
#pragma unroll
          for (int mt = 0; mt < 4; ++mt) {
            fh[s & 3][mt] = *(const uint4*)(bh_[mt] + ((s + 4) << 5));
            fl[s & 3][mt] = *(const uint4*)(bl_[mt] + ((s + 4) << 5));
          }
        }
      }
    }

    // ---- symmetric epilogue: every wave dumps full acc to slot kw
    {
      float* rp = red + (kw << 11) + lane;
#pragma unroll
      for (int mt = 0; mt < 4; ++mt)
#pragma unroll
        for (int nt = 0; nt < 2; ++nt)
#pragma unroll
          for (int r = 0; r < 4; ++r)
            rp[((mt << 3) + (nt << 2) + r) << 6] = acc[mt][nt][r];
    }
    __syncthreads();  // R1: all dumps visible

    float hsv[4], csv[4];
    {
      // wave kw finishes row-tile mt=kw: sum slots 0..3 (order == round 12)
      float g0[4], g1[4];
#pragma unroll
      for (int r = 0; r < 4; ++r) {
        const int i0x = (((kw << 3) + r) << 6) + lane;
        const int i1x = (((kw << 3) + 4 + r) << 6) + lane;
        g0[r] = red[i0x] + red[2048 + i0x] + red[4096 + i0x] + red[6144 + i0x];
        g1[r] = red[i1x] + red[2048 + i1x] + red[4096 + i1x] + red[6144 + i1x];
      }
      // ring guard: don't overwrite h slot until consumer within 32 steps
      if (layer == 0 && t >= 32) wave_wait_ge(go1, (unsigned)(t - 31));
      const int wsl = t & RMASK;
      unsigned short* hhi_d = (layer ? h1hi : h0hi) + (wsl << 16);
      unsigned short* hlo_d = (layer ? h1lo : h0lo) + (wsl << 16);
#pragma unroll
      for (int r = 0; r < 4; ++r) {
        const float a0 = g0[r], a1 = g1[r];
        const float a0x = __shfl_xor(a0, 8);
        const float a1x = __shfl_xor(a1, 8);
        const bool lo = (cl < 8);
        const float vi = (lo ? a0 : a0x) + bi;
        const float vf = (lo ? a0x : a0) + bf_;
        const float vg = (lo ? a1 : a1x) + bg;
        const float vo = (lo ? a1x : a1) + bo;
        const float ig = sigm(vi), fg = sigm(vf), gg = tanh_(vg), og = sigm(vo);
        const float cn = fg * creg[r] + ig * gg;
        creg[r] = cn;
        const float h = og * tanh_(cn);
        hsv[r] = h; csv[r] = cn;
        if (lo) {
          const int b = (kw << 4) + (rg << 2) + r;
          const int hidx = (b << 10) + j0 + u_;
          const unsigned short hb = f2bf(h);
          const unsigned short lb = f2bf(h - bf2f(hb));
          __hip_atomic_store(hhi_d + hidx, hb, __ATOMIC_RELAXED, __HIP_MEMORY_SCOPE_AGENT);
          __hip_atomic_store(hlo_d + hidx, lb, __ATOMIC_RELAXED, __HIP_MEMORY_SCOPE_AGENT);
        }
      }
      // drain h publishes ONLY (out stores not yet issued) -> fast flag
      asm volatile("s_waitcnt vmcnt(0)" ::: "memory");
    }
    __syncthreads();  // R2: all waves' h publishes drained; red free for t+1

    if (tid == 0)
      __hip_atomic_store(bar + (w << 5), e, __ATOMIC_RELAXED, __HIP_MEMORY_SCOPE_AGENT);

    // ---- deferred out stores (off the notify critical path; never read back)
    if (layer && cl < 8) {
#pragma unroll
      for (int r = 0; r < 4; ++r) {
        const int b = (kw << 4) + (rg << 2) + r;
        out[((size_t)b * SEQ + t) * HD + j0 + u_] = hsv[r];
        if (t == SEQ - 1) {
          out[OUT_H + (size_t)(b << 10) + j0 + u_] = hsv[r];
          out[OUT_C + (size_t)(b << 10) + j0 + u_] = csv[r];
        }
      }
    }

    // ---- layer leader: gather 127 peer flags, publish layer epoch
    if (tl == 0) {
      __syncthreads();  // own flag stored (tid0 passed store above)
      if (tid >= 1 && tid < 128) {
        const unsigned* pf = bar + (((layer << 7) + tid) << 5);
        while (__hip_atomic_load(pf, __ATOMIC_RELAXED, __HIP_MEMORY_SCOPE_AGENT) < e)
          __builtin_amdgcn_s_sleep(1);
      }
      __syncthreads();
      if (tid == 0)
        __hip_atomic_store(layer ? go1 : go0, e, __ATOMIC_RELAXED, __HIP_MEMORY_SCOPE_AGENT);
    }

    // ---- periodic L2 invalidate: covers h-ring slot reuse (2 invs / 32 steps)
    if ((t & 15) == 15) __builtin_amdgcn_fence(__ATOMIC_ACQUIRE, "agent");
  }
}

// prep: combined bias, zero h-ring init slot + flags/epochs (every launch)
__global__ void lstm_prep(const float* __restrict__ bih, const float* __restrict__ bhh,
                          float* __restrict__ bias,
                          unsigned short* __restrict__ h0hi, unsigned short* __restrict__ h0lo,
                          unsigned short* __restrict__ h1hi, unsigned short* __restrict__ h1lo,
                          unsigned* __restrict__ bar) {
  const size_t i0 = (size_t)blockIdx.x * blockDim.x + threadIdx.x;
  const size_t stride = (size_t)gridDim.x * blockDim.x;
  for (size_t idx = i0; idx < 8192; idx += stride) bias[idx] = bih[idx] + bhh[idx];
  const ushort4 z = make_ushort4(0, 0, 0, 0);
  const size_t so = ((size_t)RMASK << 16) >> 2;  // slot 31 base in ushort4 units
  for (size_t idx = i0; idx < 16384; idx += stride) {
    ((ushort4*)h0hi)[so + idx] = z; ((ushort4*)h0lo)[so + idx] = z;
    ((ushort4*)h1hi)[so + idx] = z; ((ushort4*)h1lo)[so + idx] = z;
  }
  for (size_t idx = i0; idx < 8256; idx += stride) bar[idx] = 0u;  // flags + go0/go1
}

extern "C" void kernel_launch(void* const* d_in, const int* in_sizes, int n_in,
                              void* d_out, int out_size, void* d_ws, size_t ws_size,
                              hipStream_t stream) {
  const float* x     = (const float*)d_in[0];
  const float* Wih_f = (const float*)d_in[1];
  const float* bih   = (const float*)d_in[2];
  const float* Whh_f = (const float*)d_in[3];
  const float* bhh   = (const float*)d_in[4];
  float* out = (float*)d_out;

  char* ws = (char*)d_ws;                                  // ~17 MB used
  float* bias           = (float*)(ws);                    // 32 KB
  unsigned* bar         = (unsigned*)(ws + 65536);         // flags + epochs (33 KB)
  unsigned short* h0hi  = (unsigned short*)(ws + (1ull << 20));                 // 4 MB each
  unsigned short* h0lo  = (unsigned short*)(ws + (1ull << 20) + (4ull << 20));
  unsigned short* h1hi  = (unsigned short*)(ws + (1ull << 20) + (8ull << 20));
  unsigned short* h1lo  = (unsigned short*)(ws + (1ull << 20) + (12ull << 20));

  hipLaunchKernelGGL(lstm_prep, dim3(256), dim3(256), 0, stream,
                     bih, bhh, bias, h0hi, h0lo, h1hi, h1lo, bar);

  hipLaunchKernelGGL(lstm_main, dim3(NWG), dim3(TPB), 0, stream,
                     x, Wih_f, Whh_f, bias, h0hi, h0lo, h1hi, h1lo, out, bar);
}

// Round 14
// 8197.760 us; speedup vs baseline: 1.3430x; 1.3430x over previous
//
#include <hip/hip_runtime.h>
#include <hip/hip_bf16.h>

#define SEQ 512
#define HD 1024
#define NWG 256
#define TPB 256
#define RED_OFF 131072
#define LDS_BYTES (131072 + 32768)
#define OUT_H 33554432ull
#define OUT_C 33619968ull
#define RMASK 31   // 32-slot h ring; inv cadence 16 covers slot reuse

typedef __bf16 bf16x8 __attribute__((ext_vector_type(8)));
typedef float f32x4 __attribute__((ext_vector_type(4)));

__device__ __forceinline__ unsigned short f2bf(float f) {
  __hip_bfloat16 b = __float2bfloat16(f);  // RNE
  return __builtin_bit_cast(unsigned short, b);
}
__device__ __forceinline__ float bf2f(unsigned short s) {
  return __builtin_bit_cast(float, (unsigned)s << 16);  // exact widen
}

__device__ __forceinline__ float sigm(float v) { return 1.f / (1.f + __expf(-v)); }
__device__ __forceinline__ float tanh_(float v) {
  float av = fabsf(v);
  float e = __expf(-2.f * av);
  float t = (1.f - e) / (1.f + e);
  return copysignf(t, v);
}

// async global->LDS, 16B/lane; COALESCED per-lane src (round-13 lesson: never
// per-lane 2KB-strided global reads in the hot loop)
__device__ __forceinline__ void gl2lds(const void* g, void* l) {
  __builtin_amdgcn_global_load_lds(
      (const __attribute__((address_space(1))) void*)g,
      (__attribute__((address_space(3))) void*)l, 16, 0, 0);
}

// per-WAVE epoch wait on a single word (ring guard only)
__device__ __forceinline__ void wave_wait_ge(const unsigned* a, unsigned v) {
  while (__hip_atomic_load(a, __ATOMIC_RELAXED, __HIP_MEMORY_SCOPE_AGENT) < v)
    __builtin_amdgcn_s_sleep(1);
  __builtin_amdgcn_wave_barrier();
  asm volatile("" ::: "memory");
}

// round-14: DIRECT peer-flag gate -- wave polls all 128 flags of a layer
// (lane l -> flags 2l, 2l+1), one L3 round-trip instead of the 2-hop
// arrival->leader->go chain. Flags are relaxed sc-bypass loads.
__device__ __forceinline__ void wave_wait_flags(const unsigned* bar, int base128,
                                                unsigned v, int lane) {
  const unsigned* p0 = bar + ((unsigned)(base128 + 2 * lane) << 5);
  const unsigned* p1 = bar + ((unsigned)(base128 + 2 * lane + 1) << 5);
  while (true) {
    const unsigned a = __hip_atomic_load(p0, __ATOMIC_RELAXED, __HIP_MEMORY_SCOPE_AGENT);
    const unsigned b = __hip_atomic_load(p1, __ATOMIC_RELAXED, __HIP_MEMORY_SCOPE_AGENT);
    if (__all(a >= v && b >= v)) break;
    __builtin_amdgcn_s_sleep(1);
  }
  __builtin_amdgcn_wave_barrier();
  asm volatile("" ::: "memory");
}

// Persistent LSTM, round-14: round-12 proven core (4 waves, K-split 4, gl2lds
// double-buffer staging, h-ring relaxed publish, symmetric epilogue) +
//  1) direct peer-flag gating (one hop less on the notify critical path)
//  2) early flag post + deferred out[] stores
// Math and operand order bit-identical to round 12.
__global__ __launch_bounds__(TPB, 1) void lstm_main(
    const float* __restrict__ x,
    const float* __restrict__ Wih_f,
    const float* __restrict__ Whh_f,
    const float* __restrict__ bias,
    unsigned short* h0hi, unsigned short* h0lo,
    unsigned short* h1hi, unsigned short* h1lo,
    float* __restrict__ out,
    unsigned* bar) {
  __shared__ char smem[LDS_BYTES];
  float* red = (float*)(smem + RED_OFF);

  unsigned* go1 = bar + 8192 + 32;   // leader-published L1 epoch (ring guard only)

  const int w = blockIdx.x;
  const int tid = threadIdx.x;
  const int layer = w >> 7;
  const int tl = w & 127;
  const int j0 = tl << 3;
  const int lane = tid & 63;
  const int kw = tid >> 6;
  const int cl = lane & 15;
  const int rg = lane >> 4;
  const int kbase = kw << 9;
  const int krel = (kw & 1) << 9;
  const bool isx = (layer == 0) && (kw < 2);

  // ---- W prologue: build hi+lo B-fragments in registers from fp32 W (RNE)
  uint4 whi[32], wlo[32];
#pragma unroll
  for (int i = 0; i < 32; ++i) {
    const int nt = i & 1, ks = i >> 1;
    const int c = nt * 16 + cl;
    const int grow = ((c >> 3) << 10) + j0 + (c & 7);
    const int kglob = kbase + (ks << 5) + (rg << 3);
    const float* src = (kglob < HD)
        ? (Wih_f + (((size_t)layer << 22) + ((size_t)grow << 10) + kglob))
        : (Whh_f + (((size_t)layer << 22) + ((size_t)grow << 10) + (kglob - HD)));
    union { unsigned short s2[8]; uint4 v; } uh, ul;
#pragma unroll
    for (int e = 0; e < 8; ++e) {
      const float vv = src[e];
      const unsigned short hb = f2bf(vv);
      uh.s2[e] = hb;
      ul.s2[e] = f2bf(vv - bf2f(hb));
    }
    whi[i] = uh.v;
    wlo[i] = ul.v;
  }

  const int u_ = cl & 7;
  const float bi  = bias[(layer << 12) + j0 + u_];
  const float bf_ = bias[(layer << 12) + 1024 + j0 + u_];
  const float bg  = bias[(layer << 12) + 2048 + j0 + u_];
  const float bo  = bias[(layer << 12) + 3072 + j0 + u_];

  float creg[4];
#pragma unroll
  for (int i = 0; i < 4; ++i) creg[i] = 0.f;

  // x staging lane constants (round-9/12 proven)
  char* stripe = smem + (kw << 14);   // buf0 stripe; buf1 = +65536
  const int xrr = lane >> 4;
  const int xjj = lane & 15;
  const int xslotE = xjj ^ xrr;       // even issues
  const int xslotO = xjj ^ (4 + xrr); // odd issues
  const int hrr = lane >> 3;
  const int hjj = lane & 7;
  const int hsw = hjj ^ hrr;          // pre-swizzled source slot (8 elems each)

  __syncthreads();

  for (int t = 0; t < SEQ; ++t) {
    const unsigned e = (unsigned)(t + 1);

    // ---- per-wave DIRECT flag gating (L0 x-waves: none)
    if (layer == 0) {
      if (kw >= 2 && t >= 1) wave_wait_flags(bar, 0, (unsigned)t, lane);    // L0 done t-1
    } else {
      if (kw < 2) wave_wait_flags(bar, 0, e, lane);                        // L0 done t
      else if (t >= 1) wave_wait_flags(bar, 128, (unsigned)t, lane);       // L1 done t-1
    }

    f32x4 acc[4][2];
#pragma unroll
    for (int mt = 0; mt < 4; ++mt) {
      acc[mt][0] = (f32x4){0.f, 0.f, 0.f, 0.f};
      acc[mt][1] = (f32x4){0.f, 0.f, 0.f, 0.f};
    }

    if (isx) {
      // ---- x path: LDS-staged fp32, trunc-split (round-12 verbatim)
      const float* pxE = x + ((size_t)(xrr * SEQ + t) << 10) + kbase + (xslotE << 2);
      const float* pxO = x + ((size_t)(xrr * SEQ + t) << 10) + kbase + (xslotO << 2);
#pragma unroll
      for (int i = 0; i < 16; ++i)
        gl2lds(((i & 1) ? pxO : pxE) + (size_t)i * 2097152, stripe + i * 1024);
#pragma unroll
      for (int s = 0; s < 8; ++s) {
        char* cb = stripe + ((s & 1) << 16);
        if (s < 7) {
          char* nb = stripe + (((s + 1) & 1) << 16);
          const int so = (s + 1) << 6;
#pragma unroll
          for (int i = 0; i < 16; ++i)
            gl2lds(((i & 1) ? pxO : pxE) + (size_t)i * 2097152 + so, nb + i * 1024);
          asm volatile("s_waitcnt vmcnt(16)" ::: "memory");
        } else {
          asm volatile("s_waitcnt vmcnt(0)" ::: "memory");
        }
#pragma unroll
        for (int ksl = 0; ksl < 2; ++ksl) {
          const int ig = (((s << 1) + ksl) << 1);
          const bf16x8 bh0 = __builtin_bit_cast(bf16x8, whi[ig]);
          const bf16x8 bh1 = __builtin_bit_cast(bf16x8, whi[ig + 1]);
          const bf16x8 bl0 = __builtin_bit_cast(bf16x8, wlo[ig]);
          const bf16x8 bl1 = __builtin_bit_cast(bf16x8, wlo[ig + 1]);
#pragma unroll
          for (int mt = 0; mt < 4; ++mt) {
            const int r = (mt << 4) + cl;
            const int a0 = (ksl << 3) + (rg << 1);
            const float4 f0 = *(const float4*)(cb + r * 256 + ((a0 ^ (cl & 7)) << 4));
            const float4 f1 = *(const float4*)(cb + r * 256 + (((a0 + 1) ^ (cl & 7)) << 4));
            union { unsigned short s2[8]; uint4 v; } uh, ul;
            const float ee[8] = {f0.x, f0.y, f0.z, f0.w, f1.x, f1.y, f1.z, f1.w};
#pragma unroll
            for (int e2 = 0; e2 < 8; ++e2) {
              const unsigned uu = __builtin_bit_cast(unsigned, ee[e2]);
              uh.s2[e2] = (unsigned short)(uu >> 16);  // trunc16 = exact bf16 hi
              ul.s2[e2] = f2bf(ee[e2] - __builtin_bit_cast(float, uu & 0xffff0000u));
            }
            const bf16x8 ah = __builtin_bit_cast(bf16x8, uh.v);
            const bf16x8 al = __builtin_bit_cast(bf16x8, ul.v);
            acc[mt][0] = __builtin_amdgcn_mfma_f32_16x16x32_bf16(ah, bh0, acc[mt][0], 0, 0, 0);
            acc[mt][1] = __builtin_amdgcn_mfma_f32_16x16x32_bf16(ah, bh1, acc[mt][1], 0, 0, 0);
            acc[mt][0] = __builtin_amdgcn_mfma_f32_16x16x32_bf16(al, bh0, acc[mt][0], 0, 0, 0);
            acc[mt][1] = __builtin_amdgcn_mfma_f32_16x16x32_bf16(al, bh1, acc[mt][1], 0, 0, 0);
            acc[mt][0] = __builtin_amdgcn_mfma_f32_16x16x32_bf16(ah, bl0, acc[mt][0], 0, 0, 0);
            acc[mt][1] = __builtin_amdgcn_mfma_f32_16x16x32_bf16(ah, bl1, acc[mt][1], 0, 0, 0);
          }
        }
      }
    } else {
      // ---- h path: gl2lds-staged bf16 hi+lo stripes (round-12 verbatim)
      const unsigned short *shi_, *slo_;
      if (layer == 0) {
        const int sl = (t - 1) & RMASK;
        shi_ = h0hi + (sl << 16); slo_ = h0lo + (sl << 16);
      } else if (kw < 2) {
        const int sl = t & RMASK;
        shi_ = h0hi + (sl << 16); slo_ = h0lo + (sl << 16);
      } else {
        const int sl = (t - 1) & RMASK;
        shi_ = h1hi + (sl << 16); slo_ = h1lo + (sl << 16);
      }
      const unsigned short* ph = shi_ + (hrr << 10) + krel + (hsw << 3);
      const unsigned short* pl = slo_ + (hrr << 10) + krel + (hsw << 3);
#pragma unroll
      for (int i = 0; i < 8; ++i) {
        gl2lds(ph + i * 8192, stripe + i * 1024);
        gl2lds(pl + i * 8192, stripe + 8192 + i * 1024);
      }
#pragma unroll
      for (int s = 0; s < 8; ++s) {
        char* cb = stripe + ((s & 1) << 16);
        if (s < 7) {
          char* nb = stripe + (((s + 1) & 1) << 16);
          const int so = (s + 1) << 6;
#pragma unroll
          for (int i = 0; i < 8; ++i) {
            gl2lds(ph + so + i * 8192, nb + i * 1024);
            gl2lds(pl + so + i * 8192, nb + 8192 + i * 1024);
          }
          asm volatile("s_waitcnt vmcnt(16)" ::: "memory");
        } else {
          asm volatile("s_waitcnt vmcnt(0)" ::: "memory");
        }
#pragma unroll
        for (int ksl = 0; ksl < 2; ++ksl) {
          const int ig = (((s << 1) + ksl) << 1);
          const bf16x8 bh0 = __builtin_bit_cast(bf16x8, whi[ig]);
          const bf16x8 bh1 = __builtin_bit_cast(bf16x8, whi[ig + 1]);
          const bf16x8 bl0 = __builtin_bit_cast(bf16x8, wlo[ig]);
          const bf16x8 bl1 = __builtin_bit_cast(bf16x8, wlo[ig + 1]);
#pragma unroll
          for (int mt = 0; mt < 4; ++mt) {
            const int r = (mt << 4) + cl;
            const unsigned off = (unsigned)(r << 7) +
                (unsigned)(((((ksl << 2) + rg)) ^ (cl & 7)) << 4);
            const bf16x8 ah = __builtin_bit_cast(bf16x8, *(const uint4*)(cb + off));
            const bf16x8 al = __builtin_bit_cast(bf16x8, *(const uint4*)(cb + 8192 + off));
            acc[mt][0] = __builtin_amdgcn_mfma_f32_16x16x32_bf16(ah, bh0, acc[mt][0], 0, 0, 0);
            acc[mt][1] = __builtin_amdgcn_mfma_f32_16x16x32_bf16(ah, bh1, acc[mt][1], 0, 0, 0);
            acc[mt][0] = __builtin_amdgcn_mfma_f32_16x16x32_bf16(al, bh0, acc[mt][0], 0, 0, 0);
            acc[mt][1] = __builtin_amdgcn_mfma_f32_16x16x32_bf16(al, bh1, acc[mt][1], 0, 0, 0);
            acc[mt][0] = __builtin_amdgcn_mfma_f32_16x16x32_bf16(ah, bl0, acc[mt][0], 0, 0, 0);
            acc[mt][1] = __builtin_amdgcn_mfma_f32_16x16x32_bf16(ah, bl1, acc[mt][1], 0, 0, 0);
          }
        }
      }
    }

    // ---- symmetric epilogue: every wave dumps full acc to slot kw
    {
      float* rp = red + (kw << 11) + lane;
#pragma unroll
      for (int mt = 0; mt < 4; ++mt)
#pragma unroll
        for (int nt = 0; nt < 2; ++nt)
#pragma unroll
          for (int r = 0; r < 4; ++r)
            rp[((mt << 3) + (nt << 2) + r) << 6] = acc[mt][nt][r];
    }
    __syncthreads();  // R1: all dumps visible

    float hsv[4], csv[4];
    {
      // wave kw finishes row-tile mt=kw: sum slots 0..3 (order == round 12)
      float g0[4], g1[4];
#pragma unroll
      for (int r = 0; r < 4; ++r) {
        const int i0x = (((kw << 3) + r) << 6) + lane;
        const int i1x = (((kw << 3) + 4 + r) << 6) + lane;
        g0[r] = red[i0x] + red[2048 + i0x] + red[4096 + i0x] + red[6144 + i0x];
        g1[r] = red[i1x] + red[2048 + i1x] + red[4096 + i1x] + red[6144 + i1x];
      }
      // ring guard: don't overwrite h slot until consumer within 32 steps
      if (layer == 0 && t >= 32) wave_wait_ge(go1, (unsigned)(t - 31));
      const int wsl = t & RMASK;
      unsigned short* hhi_d = (layer ? h1hi : h0hi) + (wsl << 16);
      unsigned short* hlo_d = (layer ? h1lo : h0lo) + (wsl << 16);
#pragma unroll
      for (int r = 0; r < 4; ++r) {
        const float a0 = g0[r], a1 = g1[r];
        const float a0x = __shfl_xor(a0, 8);
        const float a1x = __shfl_xor(a1, 8);
        const bool lo = (cl < 8);
        const float vi = (lo ? a0 : a0x) + bi;
        const float vf = (lo ? a0x : a0) + bf_;
        const float vg = (lo ? a1 : a1x) + bg;
        const float vo = (lo ? a1x : a1) + bo;
        const float ig = sigm(vi), fg = sigm(vf), gg = tanh_(vg), og = sigm(vo);
        const float cn = fg * creg[r] + ig * gg;
        creg[r] = cn;
        const float h = og * tanh_(cn);
        hsv[r] = h; csv[r] = cn;
        if (lo) {
          const int b = (kw << 4) + (rg << 2) + r;
          const int hidx = (b << 10) + j0 + u_;
          const unsigned short hb = f2bf(h);
          const unsigned short lb = f2bf(h - bf2f(hb));
          __hip_atomic_store(hhi_d + hidx, hb, __ATOMIC_RELAXED, __HIP_MEMORY_SCOPE_AGENT);
          __hip_atomic_store(hlo_d + hidx, lb, __ATOMIC_RELAXED, __HIP_MEMORY_SCOPE_AGENT);
        }
      }
      // drain h publishes ONLY (out stores not yet issued) -> fast flag
      asm volatile("s_waitcnt vmcnt(0)" ::: "memory");
    }
    __syncthreads();  // R2: all waves' h publishes drained; red free for t+1

    if (tid == 0)
      __hip_atomic_store(bar + (w << 5), e, __ATOMIC_RELAXED, __HIP_MEMORY_SCOPE_AGENT);

    // ---- deferred out stores (off the notify critical path; never read back)
    if (layer && cl < 8) {
#pragma unroll
      for (int r = 0; r < 4; ++r) {
        const int b = (kw << 4) + (rg << 2) + r;
        out[((size_t)b * SEQ + t) * HD + j0 + u_] = hsv[r];
        if (t == SEQ - 1) {
          out[OUT_H + (size_t)(b << 10) + j0 + u_] = hsv[r];
          out[OUT_C + (size_t)(b << 10) + j0 + u_] = csv[r];
        }
      }
    }

    // ---- L1 leader only: gather L1 flags, publish go1 (ring guard; off-path)
    if (tl == 0 && layer == 1) {
      __syncthreads();  // own flag stored (tid0 passed store above)
      if (tid >= 1 && tid < 128) {
        const unsigned* pf = bar + (((1 << 7) + tid) << 5);
        while (__hip_atomic_load(pf, __ATOMIC_RELAXED, __HIP_MEMORY_SCOPE_AGENT) < e)
          __builtin_amdgcn_s_sleep(1);
      }
      __syncthreads();
      if (tid == 0)
        __hip_atomic_store(go1, e, __ATOMIC_RELAXED, __HIP_MEMORY_SCOPE_AGENT);
    }

    // ---- periodic L2 invalidate: covers h-ring slot reuse (2 invs / 32 steps)
    if ((t & 15) == 15) __builtin_amdgcn_fence(__ATOMIC_ACQUIRE, "agent");
  }
}

// prep: combined bias, zero h-ring init slot + flags/epochs (every launch)
__global__ void lstm_prep(const float* __restrict__ bih, const float* __restrict__ bhh,
                          float* __restrict__ bias,
                          unsigned short* __restrict__ h0hi, unsigned short* __restrict__ h0lo,
                          unsigned short* __restrict__ h1hi, unsigned short* __restrict__ h1lo,
                          unsigned* __restrict__ bar) {
  const size_t i0 = (size_t)blockIdx.x * blockDim.x + threadIdx.x;
  const size_t stride = (size_t)gridDim.x * blockDim.x;
  for (size_t idx = i0; idx < 8192; idx += stride) bias[idx] = bih[idx] + bhh[idx];
  const ushort4 z = make_ushort4(0, 0, 0, 0);
  const size_t so = ((size_t)RMASK << 16) >> 2;  // slot 31 base in ushort4 units
  for (size_t idx = i0; idx < 16384; idx += stride) {
    ((ushort4*)h0hi)[so + idx] = z; ((ushort4*)h0lo)[so + idx] = z;
    ((ushort4*)h1hi)[so + idx] = z; ((ushort4*)h1lo)[so + idx] = z;
  }
  for (size_t idx = i0; idx < 8256; idx += stride) bar[idx] = 0u;  // flags + go
}

extern "C" void kernel_launch(void* const* d_in, const int* in_sizes, int n_in,
                              void* d_out, int out_size, void* d_ws, size_t ws_size,
                              hipStream_t stream) {
  const float* x     = (const float*)d_in[0];
  const float* Wih_f = (const float*)d_in[1];
  const float* bih   = (const float*)d_in[2];
  const float* Whh_f = (const float*)d_in[3];
  const float* bhh   = (const float*)d_in[4];
  float* out = (float*)d_out;

  char* ws = (char*)d_ws;                                  // ~17 MB used
  float* bias           = (float*)(ws);                    // 32 KB
  unsigned* bar         = (unsigned*)(ws + 65536);         // flags + epochs (33 KB)
  unsigned short* h0hi  = (unsigned short*)(ws + (1ull << 20));                 // 4 MB each
  unsigned short* h0lo  = (unsigned short*)(ws + (1ull << 20) + (4ull << 20));
  unsigned short* h1hi  = (unsigned short*)(ws + (1ull << 20) + (8ull << 20));
  unsigned short* h1lo  = (unsigned short*)(ws + (1ull << 20) + (12ull << 20));

  hipLaunchKernelGGL(lstm_prep, dim3(256), dim3(256), 0, stream,
                     bih, bhh, bias, h0hi, h0lo, h1hi, h1lo, bar);

  hipLaunchKernelGGL(lstm_main, dim3(NWG), dim3(TPB), 0, stream,
                     x, Wih_f, Whh_f, bias, h0hi, h0lo, h1hi, h1lo, out, bar);
}

// Round 15
// 6418.533 us; speedup vs baseline: 1.7153x; 1.2772x over previous
//
#include <hip/hip_runtime.h>
#include <hip/hip_bf16.h>

#define SEQ 512
#define HD 1024
#define NWG 256
#define TPB 512
#define RED_OFF 131072
#define LDS_BYTES (131072 + 32768)
#define OUT_H 33554432ull
#define OUT_C 33619968ull
#define RMASK 31
#define HSLOT 131072   // shorts per h ring slot: 64 b x 2048 (packed hi|lo per 32-chunk)

typedef __bf16 bf16x8 __attribute__((ext_vector_type(8)));
typedef float f32x4 __attribute__((ext_vector_type(4)));

__device__ __forceinline__ unsigned short f2bf(float f) {
  __hip_bfloat16 b = __float2bfloat16(f);  // RNE
  return __builtin_bit_cast(unsigned short, b);
}
__device__ __forceinline__ float bf2f(unsigned short s) {
  return __builtin_bit_cast(float, (unsigned)s << 16);
}

__device__ __forceinline__ float sigm(float v) { return 1.f / (1.f + __expf(-v)); }
__device__ __forceinline__ float tanh_(float v) {
  float av = fabsf(v);
  float e = __expf(-2.f * av);
  float t = (1.f - e) / (1.f + e);
  return copysignf(t, v);
}

__device__ __forceinline__ void gl2lds(const void* g, void* l) {
  __builtin_amdgcn_global_load_lds(
      (const __attribute__((address_space(1))) void*)g,
      (__attribute__((address_space(3))) void*)l, 16, 0, 0);
}

__device__ __forceinline__ void wave_wait_ge(const unsigned* a, unsigned v) {
  while (__hip_atomic_load(a, __ATOMIC_RELAXED, __HIP_MEMORY_SCOPE_AGENT) < v)
    __builtin_amdgcn_s_sleep(1);
  __builtin_amdgcn_wave_barrier();
  asm volatile("" ::: "memory");
}

// Round-15: 8 waves (2/SIMD, the key occupancy lever), K-split 8 (K-256/wave),
// K-32 staging steps (8 x 1KB issues, vmcnt(8) dbuf), packed h layout
// [b][k-chunk][hi32|lo32] for full-line staging, 2-round tree + 4-wave finish.
// The r10 ksl-loop bug (whi[30] OOB) is fixed: one ks per step, ig = 2s.
__global__ __launch_bounds__(TPB, 2) void lstm_main(
    const float* __restrict__ x,
    const float* __restrict__ Wih_f,
    const float* __restrict__ Whh_f,
    const float* __restrict__ bias,
    unsigned short* h0p, unsigned short* h1p,
    float* __restrict__ out,
    unsigned* bar) {
  __shared__ char smem[LDS_BYTES];
  float* red = (float*)(smem + RED_OFF);

  unsigned* go0 = bar + 8192;
  unsigned* go1 = bar + 8192 + 32;

  const int w = blockIdx.x;
  const int tid = threadIdx.x;
  const int layer = w >> 7;
  const int tl = w & 127;
  const int j0 = tl << 3;
  const int lane = tid & 63;
  const int kw = tid >> 6;            // 0..7, K-slice of 256
  const int cl = lane & 15;
  const int rg = lane >> 4;
  const int kbase = kw << 8;
  const bool isx = (layer == 0) && (kw < 4);

  // ---- W prologue: hi+lo fragments, 8 ks-chunks x 2 nt = 16 uint4 each
  uint4 whi[16], wlo[16];
#pragma unroll
  for (int i = 0; i < 16; ++i) {
    const int nt = i & 1, ks = i >> 1;
    const int c = nt * 16 + cl;
    const int grow = ((c >> 3) << 10) + j0 + (c & 7);
    const int kglob = kbase + (ks << 5) + (rg << 3);
    const float* src = (kglob < HD)
        ? (Wih_f + (((size_t)layer << 22) + ((size_t)grow << 10) + kglob))
        : (Whh_f + (((size_t)layer << 22) + ((size_t)grow << 10) + (kglob - HD)));
    union { unsigned short s2[8]; uint4 v; } uh, ul;
#pragma unroll
    for (int e = 0; e < 8; ++e) {
      const float vv = src[e];
      const unsigned short hb = f2bf(vv);
      uh.s2[e] = hb;
      ul.s2[e] = f2bf(vv - bf2f(hb));
    }
    whi[i] = uh.v;
    wlo[i] = ul.v;
  }

  const int u_ = cl & 7;
  const float bi  = bias[(layer << 12) + j0 + u_];
  const float bf_ = bias[(layer << 12) + 1024 + j0 + u_];
  const float bg  = bias[(layer << 12) + 2048 + j0 + u_];
  const float bo  = bias[(layer << 12) + 3072 + j0 + u_];

  float creg[4];
#pragma unroll
  for (int i = 0; i < 4; ++i) creg[i] = 0.f;

  char* sbase = smem + (kw << 14);    // 16KB/wave: 2 x 8KB step buffers
  const int srow = lane >> 3;         // staging row-in-group 0..7
  const int sslot = (lane & 7) ^ srow;// pre-swizzled source slot (16B units)
  const int hkc = (kw & 3) << 3;      // h chunk base (8 chunks per wave)

  __syncthreads();

  for (int t = 0; t < SEQ; ++t) {
    const unsigned e = (unsigned)(t + 1);

    if (layer == 0) {
      if (kw >= 4) wave_wait_ge(go0, (unsigned)t);          // h0[t-1]
    } else {
      if (kw < 4) wave_wait_ge(go0, e);                     // h0[t]
      else        wave_wait_ge(go1, (unsigned)t);           // h1[t-1]
    }

    f32x4 acc[4][2];
#pragma unroll
    for (int mt = 0; mt < 4; ++mt) {
      acc[mt][0] = (f32x4){0.f, 0.f, 0.f, 0.f};
      acc[mt][1] = (f32x4){0.f, 0.f, 0.f, 0.f};
    }

    if (isx) {
      // ---- x path: K-32 steps; row = 128B (32 fp32) full-line coalesced
      const float* xb = x + ((size_t)(srow * SEQ + t) << 10) + kbase + (sslot << 2);
#pragma unroll
      for (int i = 0; i < 8; ++i)
        gl2lds(xb + (size_t)i * 4194304, sbase + (i << 10));
#pragma unroll
      for (int s = 0; s < 8; ++s) {
        char* cb = sbase + ((s & 1) << 13);
        if (s < 7) {
          char* nb = sbase + (((s + 1) & 1) << 13);
#pragma unroll
          for (int i = 0; i < 8; ++i)
            gl2lds(xb + (size_t)i * 4194304 + ((s + 1) << 5), nb + (i << 10));
          asm volatile("s_waitcnt vmcnt(8)" ::: "memory");
        } else {
          asm volatile("s_waitcnt vmcnt(0)" ::: "memory");
        }
        const bf16x8 bh0 = __builtin_bit_cast(bf16x8, whi[(s << 1)]);
        const bf16x8 bh1 = __builtin_bit_cast(bf16x8, whi[(s << 1) + 1]);
        const bf16x8 bl0 = __builtin_bit_cast(bf16x8, wlo[(s << 1)]);
        const bf16x8 bl1 = __builtin_bit_cast(bf16x8, wlo[(s << 1) + 1]);
#pragma unroll
        for (int mt = 0; mt < 4; ++mt) {
          const int row = (mt << 4) + cl;
          const int wv = row & 7;
          const char* rb = cb + ((row >> 3) << 10) + (wv << 7);
          const float4 f0 = *(const float4*)(rb + (((rg << 1) ^ wv) << 4));
          const float4 f1 = *(const float4*)(rb + ((((rg << 1) | 1) ^ wv) << 4));
          union { unsigned short s2[8]; uint4 v; } uh, ul;
          const float ee[8] = {f0.x, f0.y, f0.z, f0.w, f1.x, f1.y, f1.z, f1.w};
#pragma unroll
          for (int e2 = 0; e2 < 8; ++e2) {
            const unsigned uu = __builtin_bit_cast(unsigned, ee[e2]);
            uh.s2[e2] = (unsigned short)(uu >> 16);
            ul.s2[e2] = f2bf(ee[e2] - __builtin_bit_cast(float, uu & 0xffff0000u));
          }
          const bf16x8 ah = __builtin_bit_cast(bf16x8, uh.v);
          const bf16x8 al = __builtin_bit_cast(bf16x8, ul.v);
          acc[mt][0] = __builtin_amdgcn_mfma_f32_16x16x32_bf16(ah, bh0, acc[mt][0], 0, 0, 0);
          acc[mt][1] = __builtin_amdgcn_mfma_f32_16x16x32_bf16(ah, bh1, acc[mt][1], 0, 0, 0);
          acc[mt][0] = __builtin_amdgcn_mfma_f32_16x16x32_bf16(al, bh0, acc[mt][0], 0, 0, 0);
          acc[mt][1] = __builtin_amdgcn_mfma_f32_16x16x32_bf16(al, bh1, acc[mt][1], 0, 0, 0);
          acc[mt][0] = __builtin_amdgcn_mfma_f32_16x16x32_bf16(ah, bl0, acc[mt][0], 0, 0, 0);
          acc[mt][1] = __builtin_amdgcn_mfma_f32_16x16x32_bf16(ah, bl1, acc[mt][1], 0, 0, 0);
        }
      }
    } else {
      // ---- h path: packed [b][chunk][hi32|lo32]; row = 128B full-line
      const unsigned short* hsl;
      if (layer == 0)  hsl = h0p + (size_t)((t - 1) & RMASK) * HSLOT;
      else if (kw < 4) hsl = h0p + (size_t)(t & RMASK) * HSLOT;
      else             hsl = h1p + (size_t)((t - 1) & RMASK) * HSLOT;
      const unsigned short* hb = hsl + (srow << 11) + (hkc << 6) + (sslot << 3);
#pragma unroll
      for (int i = 0; i < 8; ++i)
        gl2lds(hb + (i << 14), sbase + (i << 10));
#pragma unroll
      for (int s = 0; s < 8; ++s) {
        char* cb = sbase + ((s & 1) << 13);
        if (s < 7) {
          char* nb = sbase + (((s + 1) & 1) << 13);
#pragma unroll
          for (int i = 0; i < 8; ++i)
            gl2lds(hb + (i << 14) + ((s + 1) << 6), nb + (i << 10));
          asm volatile("s_waitcnt vmcnt(8)" ::: "memory");
        } else {
          asm volatile("s_waitcnt vmcnt(0)" ::: "memory");
        }
        const bf16x8 bh0 = __builtin_bit_cast(bf16x8, whi[(s << 1)]);
        const bf16x8 bh1 = __builtin_bit_cast(bf16x8, whi[(s << 1) + 1]);
        const bf16x8 bl0 = __builtin_bit_cast(bf16x8, wlo[(s << 1)]);
        const bf16x8 bl1 = __builtin_bit_cast(bf16x8, wlo[(s << 1) + 1]);
#pragma unroll
        for (int mt = 0; mt < 4; ++mt) {
          const int row = (mt << 4) + cl;
          const int wv = row & 7;
          const char* rb = cb + ((row >> 3) << 10) + (wv << 7);
          const bf16x8 ah = __builtin_bit_cast(bf16x8, *(const uint4*)(rb + ((rg ^ wv) << 4)));
          const bf16x8 al = __builtin_bit_cast(bf16x8, *(const uint4*)(rb + (((4 | rg) ^ wv) << 4)));
          acc[mt][0] = __builtin_amdgcn_mfma_f32_16x16x32_bf16(ah, bh0, acc[mt][0], 0, 0, 0);
          acc[mt][1] = __builtin_amdgcn_mfma_f32_16x16x32_bf16(ah, bh1, acc[mt][1], 0, 0, 0);
          acc[mt][0] = __builtin_amdgcn_mfma_f32_16x16x32_bf16(al, bh0, acc[mt][0], 0, 0, 0);
          acc[mt][1] = __builtin_amdgcn_mfma_f32_16x16x32_bf16(al, bh1, acc[mt][1], 0, 0, 0);
          acc[mt][0] = __builtin_amdgcn_mfma_f32_16x16x32_bf16(ah, bl0, acc[mt][0], 0, 0, 0);
          acc[mt][1] = __builtin_amdgcn_mfma_f32_16x16x32_bf16(ah, bl1, acc[mt][1], 0, 0, 0);
        }
      }
    }

    // ---- 2-round tree reduction (4 slots x 8KB = 32KB)
    if (kw >= 4) {
      float* rp = red + ((kw - 4) << 11) + lane;
#pragma unroll
      for (int mt = 0; mt < 4; ++mt)
#pragma unroll
        for (int nt = 0; nt < 2; ++nt)
#pragma unroll
          for (int r = 0; r < 4; ++r)
            rp[((mt << 3) + (nt << 2) + r) << 6] = acc[mt][nt][r];
    }
    __syncthreads();  // B: round-1 dumps visible
    if (kw < 4) {
      float* rp = red + (kw << 11) + lane;
#pragma unroll
      for (int mt = 0; mt < 4; ++mt)
#pragma unroll
        for (int nt = 0; nt < 2; ++nt)
#pragma unroll
          for (int r = 0; r < 4; ++r) {
            const int idx = ((mt << 3) + (nt << 2) + r) << 6;
            acc[mt][nt][r] += rp[idx];   // P = S_kw + S_{kw+4}
            rp[idx] = acc[mt][nt][r];
          }
    }
    __syncthreads();  // C: partials visible

    float hsv[4] = {0.f, 0.f, 0.f, 0.f}, csv[4] = {0.f, 0.f, 0.f, 0.f};
    if (kw < 4) {
      // finisher wave kw: row-tile mt=kw; sum = P0+P1+P2+P3 (deterministic)
      float g0[4], g1[4];
#pragma unroll
      for (int r = 0; r < 4; ++r) {
        const int i0x = (((kw << 3) + r) << 6) + lane;
        const int i1x = (((kw << 3) + 4 + r) << 6) + lane;
        g0[r] = red[i0x] + red[2048 + i0x] + red[4096 + i0x] + red[6144 + i0x];
        g1[r] = red[i1x] + red[2048 + i1x] + red[4096 + i1x] + red[6144 + i1x];
      }
      if (layer == 0 && t >= 32) wave_wait_ge(go1, (unsigned)(t - 31));
      const int wsl = t & RMASK;
      unsigned short* hd = (layer ? h1p : h0p) + (size_t)wsl * HSLOT;
      const int ch = tl >> 2;
      const int cpos = ((tl & 3) << 3) + u_;
#pragma unroll
      for (int r = 0; r < 4; ++r) {
        const float a0 = g0[r], a1 = g1[r];
        const float a0x = __shfl_xor(a0, 8);
        const float a1x = __shfl_xor(a1, 8);
        const bool lo = (cl < 8);
        const float vi = (lo ? a0 : a0x) + bi;
        const float vf = (lo ? a0x : a0) + bf_;
        const float vg = (lo ? a1 : a1x) + bg;
        const float vo = (lo ? a1x : a1) + bo;
        const float ig = sigm(vi), fg = sigm(vf), gg = tanh_(vg), og = sigm(vo);
        const float cn = fg * creg[r] + ig * gg;
        creg[r] = cn;
        const float h = og * tanh_(cn);
        hsv[r] = h; csv[r] = cn;
        if (lo) {
          const int b = (kw << 4) + (rg << 2) + r;
          const size_t hx = ((size_t)b << 11) + (ch << 6) + cpos;
          const unsigned short hb16 = f2bf(h);
          const unsigned short lb16 = f2bf(h - bf2f(hb16));
          __hip_atomic_store(hd + hx, hb16, __ATOMIC_RELAXED, __HIP_MEMORY_SCOPE_AGENT);
          __hip_atomic_store(hd + hx + 32, lb16, __ATOMIC_RELAXED, __HIP_MEMORY_SCOPE_AGENT);
        }
      }
      asm volatile("s_waitcnt vmcnt(0)" ::: "memory");  // drain h publishes
    }
    __syncthreads();  // R2: publishes drained; red free for t+1

    if (tid == 0)
      __hip_atomic_store(bar + (w << 5), e, __ATOMIC_RELAXED, __HIP_MEMORY_SCOPE_AGENT);

    // deferred out stores (finishers of layer 1; never read back)
    if (layer && kw < 4 && cl < 8) {
#pragma unroll
      for (int r = 0; r < 4; ++r) {
        const int b = (kw << 4) + (rg << 2) + r;
        out[((size_t)b * SEQ + t) * HD + j0 + u_] = hsv[r];
        if (t == SEQ - 1) {
          out[OUT_H + (size_t)(b << 10) + j0 + u_] = hsv[r];
          out[OUT_C + (size_t)(b << 10) + j0 + u_] = csv[r];
        }
      }
    }

    // layer leader: gather 127 peer flags, publish layer epoch (r12 scheme)
    if (tl == 0) {
      __syncthreads();
      if (tid >= 1 && tid < 128) {
        const unsigned* pf = bar + (((layer << 7) + tid) << 5);
        while (__hip_atomic_load(pf, __ATOMIC_RELAXED, __HIP_MEMORY_SCOPE_AGENT) < e)
          __builtin_amdgcn_s_sleep(1);
      }
      __syncthreads();
      if (tid == 0)
        __hip_atomic_store(layer ? go1 : go0, e, __ATOMIC_RELAXED, __HIP_MEMORY_SCOPE_AGENT);
    }

    if ((t & 15) == 15) __builtin_amdgcn_fence(__ATOMIC_ACQUIRE, "agent");
  }
}

// prep: combined bias, zero h-ring slot 31 (both packed buffers), flags
__global__ void lstm_prep(const float* __restrict__ bih, const float* __restrict__ bhh,
                          float* __restrict__ bias,
                          unsigned short* __restrict__ h0p, unsigned short* __restrict__ h1p,
                          unsigned* __restrict__ bar) {
  const size_t i0 = (size_t)blockIdx.x * blockDim.x + threadIdx.x;
  const size_t stride = (size_t)gridDim.x * blockDim.x;
  for (size_t idx = i0; idx < 8192; idx += stride) bias[idx] = bih[idx] + bhh[idx];
  const ushort4 z = make_ushort4(0, 0, 0, 0);
  const size_t so = ((size_t)RMASK * HSLOT) >> 2;  // slot 31 base, ushort4 units
  for (size_t idx = i0; idx < 32768; idx += stride) {
    ((ushort4*)h0p)[so + idx] = z;
    ((ushort4*)h1p)[so + idx] = z;
  }
  for (size_t idx = i0; idx < 8256; idx += stride) bar[idx] = 0u;
}

extern "C" void kernel_launch(void* const* d_in, const int* in_sizes, int n_in,
                              void* d_out, int out_size, void* d_ws, size_t ws_size,
                              hipStream_t stream) {
  const float* x     = (const float*)d_in[0];
  const float* Wih_f = (const float*)d_in[1];
  const float* bih   = (const float*)d_in[2];
  const float* Whh_f = (const float*)d_in[3];
  const float* bhh   = (const float*)d_in[4];
  float* out = (float*)d_out;

  char* ws = (char*)d_ws;                                  // ~17 MB used
  float* bias           = (float*)(ws);                    // 32 KB
  unsigned* bar         = (unsigned*)(ws + 65536);         // flags + epochs
  unsigned short* h0p   = (unsigned short*)(ws + (1ull << 20));            // 8 MB
  unsigned short* h1p   = (unsigned short*)(ws + (1ull << 20) + (8ull << 20)); // 8 MB

  hipLaunchKernelGGL(lstm_prep, dim3(256), dim3(256), 0, stream,
                     bih, bhh, bias, h0p, h1p, bar);

  hipLaunchKernelGGL(lstm_main, dim3(NWG), dim3(TPB), 0, stream,
                     x, Wih_f, Whh_f, bias, h0p, h1p, out, bar);
}